// Round 5
// baseline (210.084 us; speedup 1.0000x reference)
//
#include <hip/hip_runtime.h>
#include <math.h>

#define HW_ (512 * 512)   // 2^18
#define C_ 64
#define K_ 16
#define B_ 8

// Transpose conv_w [K][C] -> wt [C][K]; per-channel weights become 16
// contiguous floats at a wave-uniform address (scalarizes to s_load).
__global__ __launch_bounds__(256) void transpose_w_kernel(const float* __restrict__ w,
                                                          float* __restrict__ wt) {
    int i = blockIdx.x * blockDim.x + threadIdx.x;  // 0..1023
    if (i < K_ * C_) {
        int k = i >> 6;
        int c = i & 63;
        wt[c * K_ + k] = w[i];
    }
}

// Async global->LDS, 16B per lane. LDS dest is wave-uniform base + lane*16
// (we pass the per-lane pointer; lane 0's value is the base, layout matches
// the HW's linear fill). 1 KB of contiguous global per wave-instr.
__device__ __forceinline__ void gl_lds16(const float* g, float* l) {
    __builtin_amdgcn_global_load_lds(
        (const __attribute__((address_space(1))) void*)g,
        (__attribute__((address_space(3))) void*)l,
        16, 0, 0);
}

// Issue one 16-channel x-tile (16 KB): wave `wid` covers channels
// cbase+wid*4 .. cbase+wid*4+3; each gl_lds16 moves one channel row
// (256 px = 1 KB contiguous global -> 1 KB contiguous LDS).
__device__ __forceinline__ void issue_tile(const float* __restrict__ x, float* ldsbuf,
                                           int b, int cbase, int hw0, int wid, int lane) {
    const float* gp = x + (size_t)(b * C_ + cbase + wid * 4) * HW_ + hw0 + 4 * lane;
    float* lp = ldsbuf + (wid * 4) * 256 + 4 * lane;
    #pragma unroll
    for (int i = 0; i < 4; ++i)
        gl_lds16(gp + (size_t)i * HW_, lp + i * 256);
}

// Per-pixel epilogue: log_softmax form + gumbel-max, same fp expression order
// as the jax reference (byte-identical to the passing R0/R3 kernels).
__device__ __forceinline__ void epilogue(const float* acc, const float4* up4,
                                         const float* __restrict__ palette,
                                         float& cr, float& cg, float& cb) {
    float m = acc[0];
    #pragma unroll
    for (int k = 1; k < K_; ++k) m = fmaxf(m, acc[k]);
    float s = 0.0f;
    #pragma unroll
    for (int k = 0; k < K_; ++k) s += expf(acc[k] - m);
    float ls = logf(s);

    float best = -INFINITY;
    int bi = 0;
    #pragma unroll
    for (int q = 0; q < 4; ++q) {
        float4 v = up4[q];
        float g0 = -logf(-logf(v.x + 1e-20f) + 1e-20f);
        float g1 = -logf(-logf(v.y + 1e-20f) + 1e-20f);
        float g2 = -logf(-logf(v.z + 1e-20f) + 1e-20f);
        float g3 = -logf(-logf(v.w + 1e-20f) + 1e-20f);
        float t0 = (acc[q * 4 + 0] - m) - ls + g0;
        float t1 = (acc[q * 4 + 1] - m) - ls + g1;
        float t2 = (acc[q * 4 + 2] - m) - ls + g2;
        float t3 = (acc[q * 4 + 3] - m) - ls + g3;
        if (t0 > best) { best = t0; bi = q * 4 + 0; }
        if (t1 > best) { best = t1; bi = q * 4 + 1; }
        if (t2 > best) { best = t2; bi = q * 4 + 2; }
        if (t3 > best) { best = t3; bi = q * 4 + 3; }
    }
    cr = palette[bi * 3 + 0];
    cg = palette[bi * 3 + 1];
    cb = palette[bi * 3 + 2];
}

// Block = 256 threads = 256 consecutive pixels; 4 rounds (pixel-sets) per
// block. x staged through double-buffered LDS tiles via global_load_lds:
// counted vmcnt(4) keeps the next tile's 4 loads in flight across barriers.
__global__ __launch_bounds__(256, 8) void quantizer_kernel(
    const float* __restrict__ x,        // [B][C][HW]
    const float* __restrict__ wt,       // [C][K]
    const float* __restrict__ bias,     // [K]
    const float* __restrict__ palette,  // [K][3]
    const float* __restrict__ unif,     // [B*HW][K]
    float* __restrict__ out)            // [B][3][HW]
{
    __shared__ float lds[2][16 * 256];   // 2 x 16 KB

    const int t = threadIdx.x;
    const int wid = t >> 6;
    const int lane = t & 63;
    const int blk = blockIdx.x;          // 0..2047
    const int b0 = blk >> 10;            // 0 or 1
    const int hw0 = (blk & 1023) * 256;  // 1 KB-aligned pixel window

    // prologue: tile (r=0, g=0) -> buf 0
    issue_tile(x, lds[0], b0, 0, hw0, wid, lane);

    #pragma unroll 1
    for (int r = 0; r < 4; ++r) {
        const int b = b0 + 2 * r;

        float acc[K_];
        #pragma unroll
        for (int k = 0; k < K_; ++k) acc[k] = bias[k];

        #pragma unroll
        for (int g = 0; g < 4; ++g) {
            // issue next tile into the other buffer, then wait for THIS tile's
            // 4 loads (counted: leave the next tile's 4 in flight).
            if (g < 3) {
                issue_tile(x, lds[(g + 1) & 1], b, (g + 1) * 16, hw0, wid, lane);
                asm volatile("s_waitcnt vmcnt(4)" ::: "memory");
            } else if (r < 3) {
                issue_tile(x, lds[0], b0 + 2 * (r + 1), 0, hw0, wid, lane);
                asm volatile("s_waitcnt vmcnt(4)" ::: "memory");
            } else {
                asm volatile("s_waitcnt vmcnt(0)" ::: "memory");
            }
            __builtin_amdgcn_s_barrier();

            // compute this tile: 16 channels. lds read stride across lanes is
            // 4 B -> 2 lanes/bank -> conflict-free. Accumulation order per
            // (pixel,k) is ascending c == the passing R0/R3 chain.
            const float* buf = lds[g & 1];
            const float* wp = wt + (g * 16) * K_;   // wave-uniform -> s_load
            #pragma unroll
            for (int cl = 0; cl < 16; ++cl) {
                float xv = buf[cl * 256 + t];
                #pragma unroll
                for (int k = 0; k < K_; ++k)
                    acc[k] = fmaf(xv, wp[cl * K_ + k], acc[k]);
            }
            __builtin_amdgcn_s_barrier();  // buf consumed; next issue may overwrite
        }

        // epilogue for this round's pixel (overlaps the next round's in-flight tile)
        size_t p = (size_t)b * HW_ + (size_t)(hw0 + t);
        const float4* up4 = reinterpret_cast<const float4*>(unif + p * K_);
        float cr, cg, cb;
        epilogue(acc, up4, palette, cr, cg, cb);

        size_t obase = (size_t)b * 3 * HW_ + (size_t)(hw0 + t);
        out[obase]                   = cr;
        out[obase + (size_t)HW_]     = cg;
        out[obase + 2 * (size_t)HW_] = cb;
    }
}

extern "C" void kernel_launch(void* const* d_in, const int* in_sizes, int n_in,
                              void* d_out, int out_size, void* d_ws, size_t ws_size,
                              hipStream_t stream) {
    const float* x       = (const float*)d_in[0];
    const float* conv_w  = (const float*)d_in[1];
    const float* conv_b  = (const float*)d_in[2];
    const float* palette = (const float*)d_in[3];
    const float* unif    = (const float*)d_in[4];
    float* out = (float*)d_out;
    float* wt  = (float*)d_ws;   // K_*C_*4 = 4 KiB scratch

    hipLaunchKernelGGL(transpose_w_kernel, dim3(4), dim3(256), 0, stream, conv_w, wt);

    // 2048 blocks x 256 threads; each block does 4 rounds of 256 pixels.
    hipLaunchKernelGGL(quantizer_kernel, dim3(2048), dim3(256), 0, stream,
                       x, wt, conv_b, palette, unif, out);
}